// Round 7
// baseline (82.208 us; speedup 1.0000x reference)
//
#include <hip/hip_runtime.h>

// TT-linear fp32, fully fused, zero workspace. All 512 threads active in every
// phase (no wave specialization); 3 barriers.
//
// x:     [128][8192], i = i0*256 + i1*16 + i2   (i0:32, i1:16, i2:16)
// core0: c0[o0*128 + k], k = i0*4 + r1          (o0:32, r1:4)
// core1: c1[(r1*16+o1)*64 + j], j = i1*4 + r2   (o1:16, r2:4)
// core2: c2[r2*256 + o2*16 + i2]                (o2:16)
// out:   [128][8192], o = o0*256 + o1*16 + o2
//
// Block (t, o2-quarter q), 512 thr:
//   B: y1[j][col=(i0,o2l)] = sum_i2 x*c2            y1s swizzle (i0+j)&31
//   C: y2[k=(i0,r1)][dcol=(o1,o2l)] = c1 . y1       thread=(o1,i0), 4r1 x 4o2l,
//      K=64 full; c1 via broadcast VMEM.            y2s swizzle (dq+(k>>2)+4(k&3))&15
//   D: out = c0 . y2 + bias                         thread=(ks,o0q,colq), 4o0 x 1
//      K-split-4, partials in LDS (alias y1s), then reduce+bias.
// Swizzles give exactly 8 words/bank per b128 wave-access (even = floor rate).

__device__ __forceinline__ void fma4(float4& a, float s, const float4& v) {
    a.x += s*v.x; a.y += s*v.y; a.z += s*v.z; a.w += s*v.w;
}
__device__ __forceinline__ float dot4(float4 a, float4 b) {
    return a.x*b.x + a.y*b.y + a.z*b.z + a.w*b.w;
}

__global__ __launch_bounds__(512, 4) void tt_fused(
    const float* __restrict__ x, const float* __restrict__ c0,
    const float* __restrict__ c1, const float* __restrict__ c2,
    const float* __restrict__ bias, float* __restrict__ out)
{
    __shared__ __align__(16) float smem[16384];   // 64 KB
    float* y1s = smem;          // [j(64)][qc(32) at (qc+j)&31][4]
    float* y2s = smem + 8192;   // [k(128)][dq(16) at (dq+(k>>2)+4*(k&3))&15][4]
    float* pd  = smem;          // alias y1s (dead after C): [ks(4)][o0(32)][colq(16)][4]

    const int tid = threadIdx.x;
    const int b = blockIdx.x;
    const int t = b >> 2, q = b & 3;

    // ---- Phase B: all 512. thread=(i0,i1); 4 r2 outputs ---------------------
    {
        const int i0 = tid >> 4, i1 = tid & 15;
        const float* xp = x + t*8192 + i0*256 + i1*16;
        const float4 x0 = *reinterpret_cast<const float4*>(xp + 0);
        const float4 x1 = *reinterpret_cast<const float4*>(xp + 4);
        const float4 x2 = *reinterpret_cast<const float4*>(xp + 8);
        const float4 x3 = *reinterpret_cast<const float4*>(xp + 12);
#pragma unroll
        for (int r2 = 0; r2 < 4; ++r2) {
            float s[4];
#pragma unroll
            for (int o2l = 0; o2l < 4; ++o2l) {   // c2: block-uniform addr (s_load)
                const float4* cb =
                    reinterpret_cast<const float4*>(c2 + r2*256 + (q*4 + o2l)*16);
                s[o2l] = dot4(x0, cb[0]) + dot4(x1, cb[1])
                       + dot4(x2, cb[2]) + dot4(x3, cb[3]);
            }
            const int j = i1*4 + r2;
            *reinterpret_cast<float4*>(y1s + j*128 + ((i0 + j) & 31)*4) =
                make_float4(s[0], s[1], s[2], s[3]);
        }
    }
    __syncthreads();

    // ---- Phase C: all 512. thread=(o1,co=i0); tile 4 r1 x 4 o2l, K=64 ------
    {
        const int o1 = tid >> 5, co = tid & 31;
        float4 acc0 = make_float4(0,0,0,0), acc1 = acc0, acc2 = acc0, acc3 = acc0;
        const float* c1p = c1 + o1*64;            // + r1*1024 + j
#pragma unroll 2
        for (int jq = 0; jq < 16; ++jq) {
            const int j0 = jq*4;
            // c1: broadcast VMEM, 2 distinct addrs per wave-instr
            const float4 cv0 = *reinterpret_cast<const float4*>(c1p + 0*1024 + j0);
            const float4 cv1 = *reinterpret_cast<const float4*>(c1p + 1*1024 + j0);
            const float4 cv2 = *reinterpret_cast<const float4*>(c1p + 2*1024 + j0);
            const float4 cv3 = *reinterpret_cast<const float4*>(c1p + 3*1024 + j0);
            float4 yv[4];
#pragma unroll
            for (int jj = 0; jj < 4; ++jj) {
                const int j = j0 + jj;
                yv[jj] = *reinterpret_cast<const float4*>(y1s + j*128 + ((co + j) & 31)*4);
            }
            fma4(acc0, cv0.x, yv[0]); fma4(acc0, cv0.y, yv[1]);
            fma4(acc0, cv0.z, yv[2]); fma4(acc0, cv0.w, yv[3]);
            fma4(acc1, cv1.x, yv[0]); fma4(acc1, cv1.y, yv[1]);
            fma4(acc1, cv1.z, yv[2]); fma4(acc1, cv1.w, yv[3]);
            fma4(acc2, cv2.x, yv[0]); fma4(acc2, cv2.y, yv[1]);
            fma4(acc2, cv2.z, yv[2]); fma4(acc2, cv2.w, yv[3]);
            fma4(acc3, cv3.x, yv[0]); fma4(acc3, cv3.y, yv[1]);
            fma4(acc3, cv3.z, yv[2]); fma4(acc3, cv3.w, yv[3]);
        }
        // y2s[k=co*4+r1][dq=o1], phys = (o1 + co + 4*r1) & 15
        *reinterpret_cast<float4*>(y2s + (co*4+0)*64 + ((o1 + co     ) & 15)*4) = acc0;
        *reinterpret_cast<float4*>(y2s + (co*4+1)*64 + ((o1 + co +  4) & 15)*4) = acc1;
        *reinterpret_cast<float4*>(y2s + (co*4+2)*64 + ((o1 + co +  8) & 15)*4) = acc2;
        *reinterpret_cast<float4*>(y2s + (co*4+3)*64 + ((o1 + co + 12) & 15)*4) = acc3;
    }
    __syncthreads();

    // ---- Phase D: all 512. thread=(ks,o0q,colq); 4 o0 x 1 colq, K=32 -------
    {
        const int ks = tid >> 7, o0q = (tid >> 4) & 7, colq = tid & 15;
        float4 acc[4];
#pragma unroll
        for (int m = 0; m < 4; ++m) acc[m] = make_float4(0,0,0,0);
        const float* c0p = c0 + o0q*4*128;
#pragma unroll 2
        for (int kq = 0; kq < 8; ++kq) {
            const int kb = ks*32 + kq*4;
            float4 yq[4];
#pragma unroll
            for (int kk = 0; kk < 4; ++kk) {
                const int k = kb + kk;
                const int phys = (colq + (k >> 2) + 4*(k & 3)) & 15;
                yq[kk] = *reinterpret_cast<const float4*>(y2s + k*64 + phys*4);
            }
            float4 cq[4];                          // c0: 4 distinct addrs/wave (bcast)
#pragma unroll
            for (int o0l = 0; o0l < 4; ++o0l)
                cq[o0l] = *reinterpret_cast<const float4*>(c0p + o0l*128 + kb);
#pragma unroll
            for (int o0l = 0; o0l < 4; ++o0l) {
                fma4(acc[o0l], cq[o0l].x, yq[0]);
                fma4(acc[o0l], cq[o0l].y, yq[1]);
                fma4(acc[o0l], cq[o0l].z, yq[2]);
                fma4(acc[o0l], cq[o0l].w, yq[3]);
            }
        }
#pragma unroll
        for (int o0l = 0; o0l < 4; ++o0l)          // pd aliases dead y1s
            *reinterpret_cast<float4*>(pd + ks*2048 + (o0q*4 + o0l)*64 + colq*4) = acc[o0l];
    }
    __syncthreads();

    // ---- Final: all 512. Reduce 4 K-partials + bias -------------------------
    {
        const int o0 = tid >> 4, o1 = tid & 15;
        const float4 s0 = *reinterpret_cast<const float4*>(pd + 0    + o0*64 + o1*4);
        const float4 s1 = *reinterpret_cast<const float4*>(pd + 2048 + o0*64 + o1*4);
        const float4 s2 = *reinterpret_cast<const float4*>(pd + 4096 + o0*64 + o1*4);
        const float4 s3 = *reinterpret_cast<const float4*>(pd + 6144 + o0*64 + o1*4);
        const int ob = o0*256 + o1*16 + q*4;
        const float4 bq = *reinterpret_cast<const float4*>(bias + ob);
        *reinterpret_cast<float4*>(out + t*8192 + ob) =
            make_float4(s0.x+s1.x+s2.x+s3.x + bq.x,
                        s0.y+s1.y+s2.y+s3.y + bq.y,
                        s0.z+s1.z+s2.z+s3.z + bq.z,
                        s0.w+s1.w+s2.w+s3.w + bq.w);
    }
}

extern "C" void kernel_launch(void* const* d_in, const int* in_sizes, int n_in,
                              void* d_out, int out_size, void* d_ws, size_t ws_size,
                              hipStream_t stream) {
    const float* x    = (const float*)d_in[0];
    const float* c0   = (const float*)d_in[1];
    const float* c1   = (const float*)d_in[2];
    const float* c2   = (const float*)d_in[3];
    const float* bias = (const float*)d_in[4];
    float* out = (float*)d_out;
    (void)d_ws; (void)ws_size;    // no workspace — intermediates live in LDS

    tt_fused<<<512, 512, 0, stream>>>(x, c0, c1, c2, bias, out);
}